// Round 1
// baseline (82126.904 us; speedup 1.0000x reference)
//
#include <hip/hip_runtime.h>
#include <math.h>

#define IN_SIZE 96
#define HID 128
#define H3 384
#define LIN_IN 32

// ---------------------------------------------------------------------------
// Kernel A (parallel): igates[t][j] = dot(input_GRU[t,:], w_ih[j,:]) + b_ih[j]
// Block = 384 threads (one per output row j), each block covers 16 timesteps.
// input tile staged in LDS; w_ih row streamed from L2 once per block.
// ---------------------------------------------------------------------------
__global__ __launch_bounds__(384, 2)
void igates_kernel(const float* __restrict__ x, const float* __restrict__ w_ih,
                   const float* __restrict__ b_ih, float* __restrict__ ig, int T)
{
    const int TT = 16;
    int t0 = blockIdx.x * TT;
    int j = threadIdx.x; // 0..383
    __shared__ __align__(16) float xs[TT * IN_SIZE]; // 6 KB
    for (int idx = j; idx < TT * IN_SIZE; idx += H3)
        xs[idx] = x[(size_t)t0 * IN_SIZE + idx];
    __syncthreads();

    float acc[TT];
    float b = b_ih[j];
#pragma unroll
    for (int tt = 0; tt < TT; tt++) acc[tt] = b;

    const float4* w4 = (const float4*)(w_ih + (size_t)j * IN_SIZE);
#pragma unroll
    for (int k = 0; k < IN_SIZE / 4; k++) {
        float4 wv = w4[k];
#pragma unroll
        for (int tt = 0; tt < TT; tt++) {
            const float4* xv4 = (const float4*)(xs + tt * IN_SIZE);
            float4 xv = xv4[k];
            acc[tt] = fmaf(wv.x, xv.x, acc[tt]);
            acc[tt] = fmaf(wv.y, xv.y, acc[tt]);
            acc[tt] = fmaf(wv.z, xv.z, acc[tt]);
            acc[tt] = fmaf(wv.w, xv.w, acc[tt]);
        }
    }
#pragma unroll
    for (int tt = 0; tt < TT; tt++)
        ig[(size_t)(t0 + tt) * H3 + j] = acc[tt];
}

// ---------------------------------------------------------------------------
// Kernel B (sequential scan): one workgroup, 768 threads = 12 waves (3/SIMD).
// thread i -> (row = i>>1, half = i&1); holds 64 w_hh floats in VGPRs.
// Per step: matvec (64 fma/thread, h broadcast from LDS), shfl combine,
// barrier, gates on threads 0..127, readout dot on threads 0..31, barrier.
// Next-step igates/x_lin prefetched during the matvec.
// ---------------------------------------------------------------------------
__global__ __launch_bounds__(768, 3)
void scan_kernel(const float* __restrict__ ig, const float* __restrict__ xlin,
                 const float* __restrict__ h0, const float* __restrict__ w_hh,
                 const float* __restrict__ b_n, const float* __restrict__ lin_bias,
                 float* __restrict__ out, int T)
{
    __shared__ __align__(16) float h[HID];
    __shared__ float hg[H3];
    const int tid = threadIdx.x;
    const int row = tid >> 1;  // 0..383
    const int half = tid & 1;  // 0/1

    // one-time: load this thread's 64 weights into registers
    float4 w[16];
    {
        const float4* wr = (const float4*)(w_hh + (size_t)row * HID + half * 64);
#pragma unroll
        for (int k = 0; k < 16; k++) w[k] = wr[k];
    }
    if (tid < HID) h[tid] = h0[tid];

    float bn = 0.f, ig0 = 0.f, ig1 = 0.f, ig2 = 0.f, xv = 0.f;
    float lbias = lin_bias[0];
    if (tid < HID) {
        bn = b_n[tid];
        ig0 = ig[tid];
        ig1 = ig[HID + tid];
        ig2 = ig[2 * HID + tid];
    }
    if (tid < LIN_IN) xv = xlin[tid];
    __syncthreads();

    const int hbase = half * 16;
    for (int step = 0; step < T; ++step) {
        // prefetch next step's gate inputs (latency hidden by the matvec)
        float nig0 = 0.f, nig1 = 0.f, nig2 = 0.f, nxv = 0.f;
        if (step + 1 < T) {
            if (tid < HID) {
                const float* p = ig + (size_t)(step + 1) * H3;
                nig0 = p[tid];
                nig1 = p[HID + tid];
                nig2 = p[2 * HID + tid];
            }
            if (tid < LIN_IN) nxv = xlin[(size_t)(step + 1) * LIN_IN + tid];
        }

        // matvec: hg[row] = dot(w_hh[row,:], h)
        const float4* h4 = (const float4*)h;
        float a0 = 0.f, a1 = 0.f, a2 = 0.f, a3 = 0.f;
#pragma unroll
        for (int k = 0; k < 16; k++) {
            float4 hv = h4[hbase + k];
            float4 wv = w[k];
            a0 = fmaf(wv.x, hv.x, a0);
            a1 = fmaf(wv.y, hv.y, a1);
            a2 = fmaf(wv.z, hv.z, a2);
            a3 = fmaf(wv.w, hv.w, a3);
        }
        float p = (a0 + a1) + (a2 + a3);
        p += __shfl_xor(p, 1);  // combine the two K-halves
        if (half == 0) hg[row] = p;
        __syncthreads();

        // gates + state update + readout (threads 0..127 = waves 0,1)
        if (tid < HID) {
            float hr = hg[tid], hz = hg[HID + tid], hn = hg[2 * HID + tid];
            float hprev = h[tid];
            float r = 1.f / (1.f + __expf(-(ig0 + hr)));
            float z = 1.f / (1.f + __expf(-(ig1 + hz)));
            float xn = ig2 + r * (hn + bn);
            float ax = fabsf(xn);
            float e = __expf(-2.f * ax);
            float th = (1.f - e) / (1.f + e);  // tanh(|xn|), safe for large |xn|
            float nn = copysignf(th, xn);
            float hnew = nn + z * (hprev - nn);
            h[tid] = hnew;

            float po = (tid < LIN_IN) ? hnew * xv : 0.f;
            if (tid < 64) {  // wave 0: reduce lanes 0..31 (32..63 carry 0)
                po += __shfl_xor(po, 16);
                po += __shfl_xor(po, 8);
                po += __shfl_xor(po, 4);
                po += __shfl_xor(po, 2);
                po += __shfl_xor(po, 1);
                if (tid == 0) out[step] = po + lbias;
            }
        }
        ig0 = nig0; ig1 = nig1; ig2 = nig2; xv = nxv;
        __syncthreads();  // h update visible before next matvec
    }
}

extern "C" void kernel_launch(void* const* d_in, const int* in_sizes, int n_in,
                              void* d_out, int out_size, void* d_ws, size_t ws_size,
                              hipStream_t stream) {
    const float* x_gru = (const float*)d_in[0];  // (T, 96)
    const float* x_lin = (const float*)d_in[1];  // (T, 32)
    const float* h0    = (const float*)d_in[2];  // (128,)
    const float* w_ih  = (const float*)d_in[3];  // (384, 96)
    const float* w_hh  = (const float*)d_in[4];  // (384, 128)
    const float* b_ih  = (const float*)d_in[5];  // (384,)
    const float* b_n   = (const float*)d_in[6];  // (128,)
    const float* lbias = (const float*)d_in[7];  // (1,)
    float* out = (float*)d_out;                  // (T, 1)

    int T = in_sizes[0] / IN_SIZE;
    float* igates = (float*)d_ws;  // T*384 floats = 96 MiB

    igates_kernel<<<T / 16, 384, 0, stream>>>(x_gru, w_ih, b_ih, igates, T);
    scan_kernel<<<1, 768, 0, stream>>>(igates, x_lin, h0, w_hh, b_n, lbias, out, T);
}